// Round 3
// baseline (3823.762 us; speedup 1.0000x reference)
//
#include <hip/hip_runtime.h>
#include <hip/hip_bf16.h>

#define TOKENS 16384
#define DMODEL 2048
#define NEXP   64
#define KW     64                 // k-window for W staging
#define NW     (DMODEL / KW)      // 32 windows
#define NCH    (DMODEL / 4)       // 512 global 4-float chunks
#define TPB    32                 // tokens per block
#define TPW    8                  // tokens per wave

// out layout (floats): probs[T*2] | indices[T*2] | tokens_per_expert[64] | aux[1]
#define OFF_IDX  (TOKENS * 2)
#define OFF_HIST (TOKENS * 4)
#define OFF_AUX  (TOKENS * 4 + NEXP)

__device__ __forceinline__ const float* uniform_fptr(const float* p) {
    uint64_t u = (uint64_t)(uintptr_t)p;
    uint32_t lo = __builtin_amdgcn_readfirstlane((uint32_t)u);
    uint32_t hi = __builtin_amdgcn_readfirstlane((uint32_t)(u >> 32));
    return (const float*)(uintptr_t)(((uint64_t)hi << 32) | lo);
}

// touch every 64B line of this wave's 8 rows x 256B k-window (1 dword/lane)
__device__ __forceinline__ void l2pf(const float* xb, int kf, int lane) {
    float v = xb[(size_t)(lane >> 3) * DMODEL + kf + (lane & 7) * 8];
    asm volatile("" :: "v"(v));   // keep load alive (no DCE)
}

// X chunk load: 8 uniform float4 (one per token) -> s_load_dwordx4
#define LOADX(B0,B1,B2,B3,B4,B5,B6,B7, G) do {                 \
    const float* _p = xb + (size_t)(G) * 4;                    \
    B0 = *(const float4*)(_p + 0 * DMODEL);                    \
    B1 = *(const float4*)(_p + 1 * DMODEL);                    \
    B2 = *(const float4*)(_p + 2 * DMODEL);                    \
    B3 = *(const float4*)(_p + 3 * DMODEL);                    \
    B4 = *(const float4*)(_p + 4 * DMODEL);                    \
    B5 = *(const float4*)(_p + 5 * DMODEL);                    \
    B6 = *(const float4*)(_p + 6 * DMODEL);                    \
    B7 = *(const float4*)(_p + 7 * DMODEL);                    \
} while (0)

// one chunk of FMAs: W from swizzled LDS, X from SGPR quads
#define FMACH(B0,B1,B2,B3,B4,B5,B6,B7, C) do {                               \
    const int _ph = ((C) & 8) | (((C) & 7) ^ (lane & 7));                    \
    float4 wv = *(const float4*)&wt[wbuf][lane][_ph * 4];                    \
    acc[0]=fmaf(B0.x,wv.x,acc[0]); acc[0]=fmaf(B0.y,wv.y,acc[0]);            \
    acc[0]=fmaf(B0.z,wv.z,acc[0]); acc[0]=fmaf(B0.w,wv.w,acc[0]);            \
    acc[1]=fmaf(B1.x,wv.x,acc[1]); acc[1]=fmaf(B1.y,wv.y,acc[1]);            \
    acc[1]=fmaf(B1.z,wv.z,acc[1]); acc[1]=fmaf(B1.w,wv.w,acc[1]);            \
    acc[2]=fmaf(B2.x,wv.x,acc[2]); acc[2]=fmaf(B2.y,wv.y,acc[2]);            \
    acc[2]=fmaf(B2.z,wv.z,acc[2]); acc[2]=fmaf(B2.w,wv.w,acc[2]);            \
    acc[3]=fmaf(B3.x,wv.x,acc[3]); acc[3]=fmaf(B3.y,wv.y,acc[3]);            \
    acc[3]=fmaf(B3.z,wv.z,acc[3]); acc[3]=fmaf(B3.w,wv.w,acc[3]);            \
    acc[4]=fmaf(B4.x,wv.x,acc[4]); acc[4]=fmaf(B4.y,wv.y,acc[4]);            \
    acc[4]=fmaf(B4.z,wv.z,acc[4]); acc[4]=fmaf(B4.w,wv.w,acc[4]);            \
    acc[5]=fmaf(B5.x,wv.x,acc[5]); acc[5]=fmaf(B5.y,wv.y,acc[5]);            \
    acc[5]=fmaf(B5.z,wv.z,acc[5]); acc[5]=fmaf(B5.w,wv.w,acc[5]);            \
    acc[6]=fmaf(B6.x,wv.x,acc[6]); acc[6]=fmaf(B6.y,wv.y,acc[6]);            \
    acc[6]=fmaf(B6.z,wv.z,acc[6]); acc[6]=fmaf(B6.w,wv.w,acc[6]);            \
    acc[7]=fmaf(B7.x,wv.x,acc[7]); acc[7]=fmaf(B7.y,wv.y,acc[7]);            \
    acc[7]=fmaf(B7.z,wv.z,acc[7]); acc[7]=fmaf(B7.w,wv.w,acc[7]);            \
} while (0)

__global__ __launch_bounds__(256, 2) void router_kernel(
    const float* __restrict__ x,      // [T, D]
    const float* __restrict__ gw,     // [E, D]
    float* __restrict__ out,
    float* __restrict__ probsum_g,    // [64] ws accumulator (zeroed)
    float* __restrict__ hist_g)       // [64] ws accumulator (zeroed)
{
    __shared__ float wt[2][NEXP][KW];   // 32 KB, slot-swizzled W tiles
    __shared__ float psum_s[4][NEXP];
    __shared__ int   hist_s[NEXP];

    const int tid  = threadIdx.x;
    const int wave = tid >> 6;
    const int lane = tid & 63;
    const int tok0 = blockIdx.x * TPB;
    const int tokw = tok0 + wave * TPW;

    if (tid < NEXP) hist_s[tid] = 0;

    const float* xb = uniform_fptr(x + (size_t)tokw * DMODEL);

    // W staging map: thread stages 4 float4/window.
    // f = tid + i*256 ; e = f>>4 ; slot = f&15 ; phys = (slot&8)|((slot&7)^(e&7))
    int st_e[4], st_slot[4], st_phys[4];
#pragma unroll
    for (int i = 0; i < 4; ++i) {
        int f = tid + i * 256;
        st_e[i]    = f >> 4;
        st_slot[i] = f & 15;
        st_phys[i] = (st_slot[i] & 8) | ((st_slot[i] & 7) ^ (st_e[i] & 7));
    }

    float acc[8];
#pragma unroll
    for (int t = 0; t < 8; ++t) acc[t] = 0.f;

    // ---- prologue: stage W window 0, preload W window 1, warm L2 for X ----
    float4 nv0, nv1, nv2, nv3;
    {
        nv0 = *(const float4*)(gw + (size_t)st_e[0] * DMODEL + st_slot[0] * 4);
        nv1 = *(const float4*)(gw + (size_t)st_e[1] * DMODEL + st_slot[1] * 4);
        nv2 = *(const float4*)(gw + (size_t)st_e[2] * DMODEL + st_slot[2] * 4);
        nv3 = *(const float4*)(gw + (size_t)st_e[3] * DMODEL + st_slot[3] * 4);
        *(float4*)&wt[0][st_e[0]][st_phys[0] * 4] = nv0;
        *(float4*)&wt[0][st_e[1]][st_phys[1] * 4] = nv1;
        *(float4*)&wt[0][st_e[2]][st_phys[2] * 4] = nv2;
        *(float4*)&wt[0][st_e[3]][st_phys[3] * 4] = nv3;
        const float* wg1 = gw + KW;
        nv0 = *(const float4*)(wg1 + (size_t)st_e[0] * DMODEL + st_slot[0] * 4);
        nv1 = *(const float4*)(wg1 + (size_t)st_e[1] * DMODEL + st_slot[1] * 4);
        nv2 = *(const float4*)(wg1 + (size_t)st_e[2] * DMODEL + st_slot[2] * 4);
        nv3 = *(const float4*)(wg1 + (size_t)st_e[3] * DMODEL + st_slot[3] * 4);
    }
    l2pf(xb, 0, lane);
    l2pf(xb, KW, lane);
    __syncthreads();

    float4 a0,a1,a2,a3,a4,a5,a6,a7;
    float4 b0,b1,b2,b3,b4,b5,b6,b7;
    LOADX(a0,a1,a2,a3,a4,a5,a6,a7, 0);
    LOADX(b0,b1,b2,b3,b4,b5,b6,b7, 1);

    int wbuf = 0;
    for (int w = 0; w < NW; ++w) {
        // write W(w+1) (loaded last iteration), then issue loads for W(w+2)
        if (w + 1 < NW) {
            *(float4*)&wt[wbuf ^ 1][st_e[0]][st_phys[0] * 4] = nv0;
            *(float4*)&wt[wbuf ^ 1][st_e[1]][st_phys[1] * 4] = nv1;
            *(float4*)&wt[wbuf ^ 1][st_e[2]][st_phys[2] * 4] = nv2;
            *(float4*)&wt[wbuf ^ 1][st_e[3]][st_phys[3] * 4] = nv3;
        }
        if (w + 2 < NW) {
            const float* wgp = gw + (size_t)(w + 2) * KW;
            nv0 = *(const float4*)(wgp + (size_t)st_e[0] * DMODEL + st_slot[0] * 4);
            nv1 = *(const float4*)(wgp + (size_t)st_e[1] * DMODEL + st_slot[1] * 4);
            nv2 = *(const float4*)(wgp + (size_t)st_e[2] * DMODEL + st_slot[2] * 4);
            nv3 = *(const float4*)(wgp + (size_t)st_e[3] * DMODEL + st_slot[3] * 4);
        }
        if (w + 2 < NW) l2pf(xb, (w + 2) * KW, lane);

        const int g0 = w * (KW / 4);
#pragma unroll
        for (int cc = 0; cc < 8; ++cc) {
            FMACH(a0,a1,a2,a3,a4,a5,a6,a7, 2 * cc);
            if (g0 + 2 * cc + 2 < NCH)
                LOADX(a0,a1,a2,a3,a4,a5,a6,a7, g0 + 2 * cc + 2);
            FMACH(b0,b1,b2,b3,b4,b5,b6,b7, 2 * cc + 1);
            if (g0 + 2 * cc + 3 < NCH)
                LOADX(b0,b1,b2,b3,b4,b5,b6,b7, g0 + 2 * cc + 3);
        }
        __syncthreads();
        wbuf ^= 1;
    }

    // ---- epilogue: per-token softmax + top-2 across the 64 lanes ----
    float local_psum = 0.f;
#pragma unroll
    for (int t = 0; t < 8; ++t) {
        float v = acc[t];
        float m = v;
#pragma unroll
        for (int off = 32; off; off >>= 1) m = fmaxf(m, __shfl_xor(m, off));
        float ex = __expf(v - m);
        float S = ex;
#pragma unroll
        for (int off = 32; off; off >>= 1) S += __shfl_xor(S, off);
        local_psum += ex / S;

        float bv = v; int bi = lane;
#pragma unroll
        for (int off = 32; off; off >>= 1) {
            float ov = __shfl_xor(bv, off);
            int   oi = __shfl_xor(bi, off);
            if (ov > bv || (ov == bv && oi < bi)) { bv = ov; bi = oi; }
        }
        float v1 = bv; int i1 = bi;
        float bv2 = (lane == i1) ? -3.4e38f : v; int bi2 = lane;
#pragma unroll
        for (int off = 32; off; off >>= 1) {
            float ov = __shfl_xor(bv2, off);
            int   oi = __shfl_xor(bi2, off);
            if (ov > bv2 || (ov == bv2 && oi < bi2)) { bv2 = ov; bi2 = oi; }
        }
        float v2 = bv2; int i2 = bi2;

        if (lane == 0) {
            float e1 = __expf(v1 - m);
            float e2 = __expf(v2 - m);
            float inv = 1.f / (e1 + e2);
            int tok = tokw + t;
            out[tok * 2 + 0] = e1 * inv;
            out[tok * 2 + 1] = e2 * inv;
            out[OFF_IDX + tok * 2 + 0] = (float)i1;
            out[OFF_IDX + tok * 2 + 1] = (float)i2;
            atomicAdd(&hist_s[i1], 1);
            atomicAdd(&hist_s[i2], 1);
        }
    }

    psum_s[wave][lane] = local_psum;
    __syncthreads();
    if (wave == 0) {
        float s = psum_s[0][lane] + psum_s[1][lane] + psum_s[2][lane] + psum_s[3][lane];
        atomicAdd(&probsum_g[lane], s);
        atomicAdd(&hist_g[lane], (float)hist_s[lane]);
    }
}

__global__ void finalize_kernel(const float* __restrict__ probsum_g,
                                const float* __restrict__ hist_g,
                                float* __restrict__ out)
{
    int e = threadIdx.x;  // 64 threads
    float tpe = hist_g[e];
    out[OFF_HIST + e] = tpe;
    const float invT = 1.f / (float)TOKENS;
    float term = (tpe * invT) * (probsum_g[e] * invT);
#pragma unroll
    for (int off = 32; off; off >>= 1) term += __shfl_xor(term, off);
    if (e == 0) out[OFF_AUX] = term * (float)NEXP;
}

extern "C" void kernel_launch(void* const* d_in, const int* in_sizes, int n_in,
                              void* d_out, int out_size, void* d_ws, size_t ws_size,
                              hipStream_t stream) {
    const float* x  = (const float*)d_in[0];
    const float* gw = (const float*)d_in[1];
    float* out = (float*)d_out;
    float* ws  = (float*)d_ws;   // probsum[64] | hist[64]

    hipMemsetAsync(d_ws, 0, 128 * sizeof(float), stream);

    dim3 grid(TOKENS / TPB);     // 512 blocks x 256 threads (4 waves)
    router_kernel<<<grid, 256, 0, stream>>>(x, gw, out, ws, ws + NEXP);
    finalize_kernel<<<1, 64, 0, stream>>>(ws, ws + NEXP, out);
}

// Round 4
// 271.753 us; speedup vs baseline: 14.0707x; 14.0707x over previous
//
#include <hip/hip_runtime.h>
#include <hip/hip_bf16.h>

#define TOKENS 16384
#define DMODEL 2048
#define NEXP   64
#define KW     64                 // k-window staged in LDS for W
#define NW     (DMODEL / KW)      // 32 windows
#define TPB    32                 // tokens per block
#define TPW    8                  // tokens per wave

// out layout (floats): probs[T*2] | indices[T*2] | tokens_per_expert[64] | aux[1]
#define OFF_IDX  (TOKENS * 2)
#define OFF_HIST (TOKENS * 4)
#define OFF_AUX  (TOKENS * 4 + NEXP)

// touch the 64B lines of this wave's 8 rows x 256B k-window (keeps L2 warm for s_loads)
__device__ __forceinline__ void l2pf(const float* __restrict__ x, int tko, int kf, int lane) {
    float v = x[(size_t)(tko + (lane >> 3)) * DMODEL + kf + ((lane & 3) << 4)];
    asm volatile("" :: "v"(v));   // keep the load alive (no DCE)
}

// X chunk load: 8 uniform float4 (one per token). xb is a uniform pointer
// (kernel-arg base + readfirstlane'd integer offset) -> s_load_dwordx4.
#define LOADX(B0,B1,B2,B3,B4,B5,B6,B7, G) do {                 \
    const float* _p = xb + (size_t)(G) * 4;                    \
    B0 = *(const float4*)(_p + 0 * DMODEL);                    \
    B1 = *(const float4*)(_p + 1 * DMODEL);                    \
    B2 = *(const float4*)(_p + 2 * DMODEL);                    \
    B3 = *(const float4*)(_p + 3 * DMODEL);                    \
    B4 = *(const float4*)(_p + 4 * DMODEL);                    \
    B5 = *(const float4*)(_p + 5 * DMODEL);                    \
    B6 = *(const float4*)(_p + 6 * DMODEL);                    \
    B7 = *(const float4*)(_p + 7 * DMODEL);                    \
} while (0)

// one within-window chunk C (0..15) of FMAs: W from swizzled LDS (per-lane b128),
// X scalar operands from the SGPR banks. 1 SGPR read per v_fma -> legal.
#define FMACH(B0,B1,B2,B3,B4,B5,B6,B7, C) do {                               \
    const int _ph = ((C) & 8) | (((C) & 7) ^ (lane & 7));                    \
    float4 wv = *(const float4*)&wt[wbuf][lane][_ph * 4];                    \
    acc[0]=fmaf(B0.x,wv.x,acc[0]); acc[0]=fmaf(B0.y,wv.y,acc[0]);            \
    acc[0]=fmaf(B0.z,wv.z,acc[0]); acc[0]=fmaf(B0.w,wv.w,acc[0]);            \
    acc[1]=fmaf(B1.x,wv.x,acc[1]); acc[1]=fmaf(B1.y,wv.y,acc[1]);            \
    acc[1]=fmaf(B1.z,wv.z,acc[1]); acc[1]=fmaf(B1.w,wv.w,acc[1]);            \
    acc[2]=fmaf(B2.x,wv.x,acc[2]); acc[2]=fmaf(B2.y,wv.y,acc[2]);            \
    acc[2]=fmaf(B2.z,wv.z,acc[2]); acc[2]=fmaf(B2.w,wv.w,acc[2]);            \
    acc[3]=fmaf(B3.x,wv.x,acc[3]); acc[3]=fmaf(B3.y,wv.y,acc[3]);            \
    acc[3]=fmaf(B3.z,wv.z,acc[3]); acc[3]=fmaf(B3.w,wv.w,acc[3]);            \
    acc[4]=fmaf(B4.x,wv.x,acc[4]); acc[4]=fmaf(B4.y,wv.y,acc[4]);            \
    acc[4]=fmaf(B4.z,wv.z,acc[4]); acc[4]=fmaf(B4.w,wv.w,acc[4]);            \
    acc[5]=fmaf(B5.x,wv.x,acc[5]); acc[5]=fmaf(B5.y,wv.y,acc[5]);            \
    acc[5]=fmaf(B5.z,wv.z,acc[5]); acc[5]=fmaf(B5.w,wv.w,acc[5]);            \
    acc[6]=fmaf(B6.x,wv.x,acc[6]); acc[6]=fmaf(B6.y,wv.y,acc[6]);            \
    acc[6]=fmaf(B6.z,wv.z,acc[6]); acc[6]=fmaf(B6.w,wv.w,acc[6]);            \
    acc[7]=fmaf(B7.x,wv.x,acc[7]); acc[7]=fmaf(B7.y,wv.y,acc[7]);            \
    acc[7]=fmaf(B7.z,wv.z,acc[7]); acc[7]=fmaf(B7.w,wv.w,acc[7]);            \
} while (0)

// consume banks A(g0+2ci), B(g0+2ci+1); reload them 2 chunks ahead (guard-free)
#define PAIR(G0, CI) do {                                                    \
    FMACH(a0,a1,a2,a3,a4,a5,a6,a7, (2*(CI)));                                \
    LOADX(a0,a1,a2,a3,a4,a5,a6,a7, (G0) + 2*(CI) + 2);                       \
    FMACH(b0,b1,b2,b3,b4,b5,b6,b7, (2*(CI)+1));                              \
    LOADX(b0,b1,b2,b3,b4,b5,b6,b7, (G0) + 2*(CI) + 3);                       \
} while (0)

#define PAIRNL(CI) do {                                                      \
    FMACH(a0,a1,a2,a3,a4,a5,a6,a7, (2*(CI)));                                \
    FMACH(b0,b1,b2,b3,b4,b5,b6,b7, (2*(CI)+1));                              \
} while (0)

__global__ __launch_bounds__(256, 2) void router_kernel(
    const float* __restrict__ x,      // [T, D]
    const float* __restrict__ gw,     // [E, D]
    float* __restrict__ out,
    float* __restrict__ probsum_g,    // [64] ws accumulator (zeroed)
    float* __restrict__ hist_g)       // [64] ws accumulator (zeroed)
{
    __shared__ __attribute__((aligned(16))) float wt[2][NEXP][KW];  // 32 KB swizzled W dbuf
    __shared__ float psum_s[4][NEXP];
    __shared__ int   hist_s[NEXP];

    const int tid  = threadIdx.x;
    const int wave = tid >> 6;
    const int lane = tid & 63;
    const int tok0 = blockIdx.x * TPB;
    // uniform integer token offset -> uniform pointer with clean provenance
    const int tko  = __builtin_amdgcn_readfirstlane(tok0 + wave * TPW);
    const float* xb = x + (size_t)tko * DMODEL;

    if (tid < NEXP) hist_s[tid] = 0;

    // W staging map: thread stages 4 float4/window.
    // f = tid + i*256 ; e = f>>4 ; slot = f&15 ; phys = (slot&8)|((slot&7)^(e&7))
    int st_e[4], st_slot[4], st_phys[4];
#pragma unroll
    for (int i = 0; i < 4; ++i) {
        int f = tid + i * 256;
        st_e[i]    = f >> 4;
        st_slot[i] = f & 15;
        st_phys[i] = (st_slot[i] & 8) | ((st_slot[i] & 7) ^ (st_e[i] & 7));
    }

    float acc[8];
#pragma unroll
    for (int t = 0; t < 8; ++t) acc[t] = 0.f;

    // ---- prologue: stage W window 0, preload W window 1, warm L2 for X w0,w1 ----
    float4 nv0, nv1, nv2, nv3;
    {
        nv0 = *(const float4*)(gw + (size_t)st_e[0] * DMODEL + st_slot[0] * 4);
        nv1 = *(const float4*)(gw + (size_t)st_e[1] * DMODEL + st_slot[1] * 4);
        nv2 = *(const float4*)(gw + (size_t)st_e[2] * DMODEL + st_slot[2] * 4);
        nv3 = *(const float4*)(gw + (size_t)st_e[3] * DMODEL + st_slot[3] * 4);
        *(float4*)&wt[0][st_e[0]][st_phys[0] * 4] = nv0;
        *(float4*)&wt[0][st_e[1]][st_phys[1] * 4] = nv1;
        *(float4*)&wt[0][st_e[2]][st_phys[2] * 4] = nv2;
        *(float4*)&wt[0][st_e[3]][st_phys[3] * 4] = nv3;
        const float* wg1 = gw + KW;
        nv0 = *(const float4*)(wg1 + (size_t)st_e[0] * DMODEL + st_slot[0] * 4);
        nv1 = *(const float4*)(wg1 + (size_t)st_e[1] * DMODEL + st_slot[1] * 4);
        nv2 = *(const float4*)(wg1 + (size_t)st_e[2] * DMODEL + st_slot[2] * 4);
        nv3 = *(const float4*)(wg1 + (size_t)st_e[3] * DMODEL + st_slot[3] * 4);
    }
    l2pf(x, tko, 0, lane);
    l2pf(x, tko, KW, lane);
    __syncthreads();

    float4 a0,a1,a2,a3,a4,a5,a6,a7;
    float4 b0,b1,b2,b3,b4,b5,b6,b7;
    LOADX(a0,a1,a2,a3,a4,a5,a6,a7, 0);
    LOADX(b0,b1,b2,b3,b4,b5,b6,b7, 1);

    int wbuf = 0;
    for (int w = 0; w < NW - 1; ++w) {
        // write W(w+1) (regs already in flight), then issue loads for W(w+2)
        *(float4*)&wt[wbuf ^ 1][st_e[0]][st_phys[0] * 4] = nv0;
        *(float4*)&wt[wbuf ^ 1][st_e[1]][st_phys[1] * 4] = nv1;
        *(float4*)&wt[wbuf ^ 1][st_e[2]][st_phys[2] * 4] = nv2;
        *(float4*)&wt[wbuf ^ 1][st_e[3]][st_phys[3] * 4] = nv3;
        if (w + 2 < NW) {
            const float* wgp = gw + (size_t)(w + 2) * KW;
            nv0 = *(const float4*)(wgp + (size_t)st_e[0] * DMODEL + st_slot[0] * 4);
            nv1 = *(const float4*)(wgp + (size_t)st_e[1] * DMODEL + st_slot[1] * 4);
            nv2 = *(const float4*)(wgp + (size_t)st_e[2] * DMODEL + st_slot[2] * 4);
            nv3 = *(const float4*)(wgp + (size_t)st_e[3] * DMODEL + st_slot[3] * 4);
            l2pf(x, tko, (w + 2) * KW, lane);
        }

        const int g0 = w * 16;
        PAIR(g0, 0); PAIR(g0, 1); PAIR(g0, 2); PAIR(g0, 3);
        PAIR(g0, 4); PAIR(g0, 5); PAIR(g0, 6); PAIR(g0, 7);

        __syncthreads();
        wbuf ^= 1;
    }
    {   // final window, peeled: no staging, last pair consume-only
        const int g0 = (NW - 1) * 16;
        PAIR(g0, 0); PAIR(g0, 1); PAIR(g0, 2); PAIR(g0, 3);
        PAIR(g0, 4); PAIR(g0, 5); PAIR(g0, 6);
        PAIRNL(7);
    }

    // ---- epilogue: per-token softmax + top-2 across the 64 lanes ----
    float local_psum = 0.f;
#pragma unroll
    for (int t = 0; t < 8; ++t) {
        float v = acc[t];
        float m = v;
#pragma unroll
        for (int off = 32; off; off >>= 1) m = fmaxf(m, __shfl_xor(m, off));
        float ex = __expf(v - m);
        float S = ex;
#pragma unroll
        for (int off = 32; off; off >>= 1) S += __shfl_xor(S, off);
        local_psum += ex / S;

        float bv = v; int bi = lane;
#pragma unroll
        for (int off = 32; off; off >>= 1) {
            float ov = __shfl_xor(bv, off);
            int   oi = __shfl_xor(bi, off);
            if (ov > bv || (ov == bv && oi < bi)) { bv = ov; bi = oi; }
        }
        float v1 = bv; int i1 = bi;
        float bv2 = (lane == i1) ? -3.4e38f : v; int bi2 = lane;
#pragma unroll
        for (int off = 32; off; off >>= 1) {
            float ov = __shfl_xor(bv2, off);
            int   oi = __shfl_xor(bi2, off);
            if (ov > bv2 || (ov == bv2 && oi < bi2)) { bv2 = ov; bi2 = oi; }
        }
        float v2 = bv2; int i2 = bi2;

        if (lane == 0) {
            float e1 = __expf(v1 - m);
            float e2 = __expf(v2 - m);
            float inv = 1.f / (e1 + e2);
            int tok = tko + t;
            out[tok * 2 + 0] = e1 * inv;
            out[tok * 2 + 1] = e2 * inv;
            out[OFF_IDX + tok * 2 + 0] = (float)i1;
            out[OFF_IDX + tok * 2 + 1] = (float)i2;
            atomicAdd(&hist_s[i1], 1);
            atomicAdd(&hist_s[i2], 1);
        }
    }

    psum_s[wave][lane] = local_psum;
    __syncthreads();
    if (wave == 0) {
        float s = psum_s[0][lane] + psum_s[1][lane] + psum_s[2][lane] + psum_s[3][lane];
        atomicAdd(&probsum_g[lane], s);
        atomicAdd(&hist_g[lane], (float)hist_s[lane]);
    }
}

__global__ void finalize_kernel(const float* __restrict__ probsum_g,
                                const float* __restrict__ hist_g,
                                float* __restrict__ out)
{
    int e = threadIdx.x;  // 64 threads
    float tpe = hist_g[e];
    out[OFF_HIST + e] = tpe;
    const float invT = 1.f / (float)TOKENS;
    float term = (tpe * invT) * (probsum_g[e] * invT);
#pragma unroll
    for (int off = 32; off; off >>= 1) term += __shfl_xor(term, off);
    if (e == 0) out[OFF_AUX] = term * (float)NEXP;
}

extern "C" void kernel_launch(void* const* d_in, const int* in_sizes, int n_in,
                              void* d_out, int out_size, void* d_ws, size_t ws_size,
                              hipStream_t stream) {
    const float* x  = (const float*)d_in[0];
    const float* gw = (const float*)d_in[1];
    float* out = (float*)d_out;
    float* ws  = (float*)d_ws;   // probsum[64] | hist[64]

    hipMemsetAsync(d_ws, 0, 128 * sizeof(float), stream);

    dim3 grid(TOKENS / TPB);     // 512 blocks x 256 threads (4 waves)
    router_kernel<<<grid, 256, 0, stream>>>(x, gw, out, ws, ws + NEXP);
    finalize_kernel<<<1, 64, 0, stream>>>(ws, ws + NEXP, out);
}